// Round 4
// baseline (51195.535 us; speedup 1.0000x reference)
//
#include <hip/hip_runtime.h>
#include <stdint.h>

// ---------------------------------------------------------------------------
// Bidirectional 2-layer LSTM.
//  Phase A: xg = x . W_ih^T + b (bf16 MFMA GEMM)  [unchanged from R2 - proven]
//  Phase B: scan. Group = (scan, batch-half of 16 rows). Each group = 2 WGs
//   of 512 thr (8 waves); WG owns 128 units x 4 gates, W_hh bf16 resident
//   (128 VGPR/wave). Own unit-half h broadcast via LDS + raw s_barrier
//   (lgkmcnt-only wait: NO vmcnt drain). Partner half via tagged u64
//   {u32 step-tag, 2xbf16} relaxed agent atomics: 16 loads/lane/attempt,
//   first attempt issued before own-half MFMA to hide the RT.
// MFMA 16x16x32 bf16:  A: lane=(m=lane&15, k=quad*8+j)  B: (k=quad*8+j, n=lane&15)
//                      C/D: (row=quad*4+reg, col=lane&15)
// ---------------------------------------------------------------------------

#define Bn 32
#define Tn 2048
#define Hn 256

typedef short short8 __attribute__((ext_vector_type(8)));
typedef float f32x4 __attribute__((ext_vector_type(4)));

__device__ inline unsigned short f2b(float f) {  // fp32 -> bf16 RNE
  union { float f; unsigned u; } v; v.f = f;
  unsigned r = v.u + 0x7fffu + ((v.u >> 16) & 1u);
  return (unsigned short)(r >> 16);
}
__device__ inline float b2f(unsigned short b) {
  union { unsigned u; float f; } v; v.u = ((unsigned)b) << 16;
  return v.f;
}
__device__ inline float sigx(float x) {
  return __builtin_amdgcn_rcpf(1.f + __expf(-x));
}
__device__ inline float tanhx(float x) {
  return 2.f * __builtin_amdgcn_rcpf(1.f + __expf(-2.f * x)) - 1.f;
}

// ---------------- Phase A: xg = A . W^T + b (R2-proven) -------------------
template <int K, bool AF32>
__global__ __launch_bounds__(256, 2) void xg_gemm(
    const void* __restrict__ Ain,
    const float* __restrict__ Wf, const float* __restrict__ bf_,
    const float* __restrict__ Wr, const float* __restrict__ br_,
    unsigned short* __restrict__ xg) {
  constexpr int KI = K / 32;
  const int bid = blockIdx.x;
  const int scan = bid & 1;
  const int sgrp = (bid >> 1) & 7;
  const int mchunk = bid >> 4;
  const int wave = threadIdx.x >> 6;
  const int lane = threadIdx.x & 63;
  const int l15 = lane & 15, quad = lane >> 4;
  const int stripe = sgrp * 4 + wave;
  const int gi0 = stripe * 32;

  const float* W = scan ? Wr : Wf;
  const float* bias = scan ? br_ : bf_;

  short8 bfr[KI][2];
  float bias2[2];
#pragma unroll
  for (int sub = 0; sub < 2; ++sub) {
    const int gi = gi0 + sub * 16 + l15;
    bias2[sub] = bias[gi];
#pragma unroll
    for (int ki = 0; ki < KI; ++ki) {
      const float* src = W + (size_t)gi * K + ki * 32 + quad * 8;
      short8 v;
#pragma unroll
      for (int j = 0; j < 8; ++j) v[j] = (short)f2b(src[j]);
      bfr[ki][sub] = v;
    }
  }

  const size_t scan_off = (size_t)scan << 26;
#pragma unroll 1
  for (int mt0 = 0; mt0 < 16; ++mt0) {
    const int mt = mchunk * 16 + mt0;
    const size_t row = (size_t)mt * 16 + l15;
    f32x4 acc[2];
#pragma unroll
    for (int sub = 0; sub < 2; ++sub) {
      f32x4 bi = {bias2[sub], bias2[sub], bias2[sub], bias2[sub]};
      acc[sub] = bi;
    }
#pragma unroll
    for (int ki = 0; ki < KI; ++ki) {
      short8 af;
      if constexpr (AF32) {
        const float* ap = (const float*)Ain + row * K + ki * 32 + quad * 8;
        f32x4 a0 = *(const f32x4*)ap;
        f32x4 a1 = *(const f32x4*)(ap + 4);
#pragma unroll
        for (int j = 0; j < 4; ++j) { af[j] = (short)f2b(a0[j]); af[4 + j] = (short)f2b(a1[j]); }
      } else {
        const unsigned short* ap = (const unsigned short*)Ain + row * K + ki * 32 + quad * 8;
        af = *(const short8*)ap;
      }
#pragma unroll
      for (int sub = 0; sub < 2; ++sub)
        acc[sub] = __builtin_amdgcn_mfma_f32_16x16x32_bf16(af, bfr[ki][sub], acc[sub], 0, 0, 0);
    }
#pragma unroll
    for (int sub = 0; sub < 2; ++sub) {
      const int gi = gi0 + sub * 16 + l15;
#pragma unroll
      for (int r = 0; r < 4; ++r) {
        const int orow = mt * 16 + quad * 4 + r;
        const int m = orow >> 11, t = orow & 2047;
        xg[scan_off + ((size_t)t * Bn + m) * 1024 + gi] = f2b(acc[sub][r]);
      }
    }
  }
}

// ---------------- Phase B: recurrent scan ---------------------------------
// box: [2scan][2mh][2uh] x [2 parity][16 m][64 pairs] u64
template <bool LAYER1>
__global__ __launch_bounds__(512, 2) void lstm_scan(
    const unsigned short* __restrict__ xg,
    const float* __restrict__ Whh_f, const float* __restrict__ Whh_r,
    unsigned long long* __restrict__ box,
    unsigned short* __restrict__ h0out,   // [B][T][512] bf16 (layer0)
    float* __restrict__ dout) {           // [B][T][512] f32  (layer1)
  const int bid = blockIdx.x;
  const int scan = bid & 1, mh = (bid >> 1) & 1, uh = bid >> 2;
  const int tid = threadIdx.x;
  const int w = tid >> 6, lane = tid & 63;
  const int l15 = lane & 15, quad = lane >> 4;
  const int Ul = w * 16 + l15;          // local unit 0..127
  const int U = uh * 128 + Ul;          // global unit 0..255
  const float* Whh = scan ? Whh_r : Whh_f;

  __shared__ unsigned short ldsb[4096]; // 2 parity x [4ki][4quad][16m] x 8 shorts

  // resident W_hh B-frags, full K: 8ki x 4g x 4 VGPR = 128 VGPRs
  short8 bfh[8][4];
#pragma unroll
  for (int ki = 0; ki < 8; ++ki) {
#pragma unroll
    for (int g = 0; g < 4; ++g) {
      const float* src = Whh + (size_t)(g * Hn + U) * Hn + ki * 32 + quad * 8;
      short8 v;
#pragma unroll
      for (int j = 0; j < 8; ++j) v[j] = (short)f2b(src[j]);
      bfh[ki][g] = v;
    }
  }

  unsigned long long* mybox = box + ((size_t)((scan * 2 + mh) * 2 + uh)) * 2048;
  const unsigned long long* pbox = box + ((size_t)((scan * 2 + mh) * 2 + (uh ^ 1))) * 2048;

  const size_t scan_off = (size_t)scan << 26;
  float c_st[4] = {0.f, 0.f, 0.f, 0.f};

  // preload xg for s=0
  unsigned short xgv[16];
  {
    const int t0 = scan ? (Tn - 1) : 0;
    const unsigned short* xp = xg + scan_off + (size_t)t0 * (Bn * 1024);
#pragma unroll
    for (int g = 0; g < 4; ++g)
#pragma unroll
      for (int r = 0; r < 4; ++r)
        xgv[g * 4 + r] = xp[(mh * 16 + quad * 4 + r) * 1024 + g * Hn + U];
  }

  for (int s = 0; s < Tn; ++s) {
    const int t = scan ? (Tn - 1 - s) : s;

    f32x4 acc[4];
#pragma unroll
    for (int g = 0; g < 4; ++g)
#pragma unroll
      for (int r = 0; r < 4; ++r)
        acc[g][r] = b2f(xgv[g * 4 + r]);

    unsigned long long q[4][4];
    if (s > 0) {
      const int par = (s - 1) & 1;
      const unsigned long long* src = pbox + par * 1024 + l15 * 64 + quad * 4;
      // attempt 0 issued BEFORE own-half MFMA (RT hides under compute)
#pragma unroll
      for (int kp = 0; kp < 4; ++kp)
#pragma unroll
        for (int j = 0; j < 4; ++j)
          q[kp][j] = __hip_atomic_load(src + kp * 16 + j,
                                       __ATOMIC_RELAXED, __HIP_MEMORY_SCOPE_AGENT);
      // own-half MFMA from LDS (parity par, written before last barrier)
#pragma unroll
      for (int ko = 0; ko < 4; ++ko) {
        short8 a = *(const short8*)&ldsb[par * 2048 + ((ko * 4 + quad) * 16 + l15) * 8];
#pragma unroll
        for (int g = 0; g < 4; ++g)
          acc[g] = __builtin_amdgcn_mfma_f32_16x16x32_bf16(a, bfh[uh * 4 + ko][g], acc[g], 0, 0, 0);
      }
      // validate attempt 0; retry until all 16 tags == s
      bool ok = true;
#pragma unroll
      for (int kp = 0; kp < 4; ++kp)
#pragma unroll
        for (int j = 0; j < 4; ++j)
          ok &= ((unsigned)(q[kp][j] >> 32) == (unsigned)s);
      int att = 0;
      while (!__all(ok)) {
        if (++att > 2) __builtin_amdgcn_s_sleep(1);
#pragma unroll
        for (int kp = 0; kp < 4; ++kp)
#pragma unroll
          for (int j = 0; j < 4; ++j)
            q[kp][j] = __hip_atomic_load(src + kp * 16 + j,
                                         __ATOMIC_RELAXED, __HIP_MEMORY_SCOPE_AGENT);
        ok = true;
#pragma unroll
        for (int kp = 0; kp < 4; ++kp)
#pragma unroll
          for (int j = 0; j < 4; ++j)
            ok &= ((unsigned)(q[kp][j] >> 32) == (unsigned)s);
      }
    }

    // prefetch xg for s+1 (latency hides under MFMA+gates+barrier)
    {
      const int sn = (s + 1 < Tn) ? s + 1 : s;
      const int tn = scan ? (Tn - 1 - sn) : sn;
      const unsigned short* xp = xg + scan_off + (size_t)tn * (Bn * 1024);
#pragma unroll
      for (int g = 0; g < 4; ++g)
#pragma unroll
        for (int r = 0; r < 4; ++r)
          xgv[g * 4 + r] = xp[(mh * 16 + quad * 4 + r) * 1024 + g * Hn + U];
    }

    if (s > 0) {
      // partner-half MFMA from tagged pairs
#pragma unroll
      for (int kp = 0; kp < 4; ++kp) {
        union { unsigned u[4]; short8 s8; } uu;
#pragma unroll
        for (int j = 0; j < 4; ++j) uu.u[j] = (unsigned)q[kp][j];
#pragma unroll
        for (int g = 0; g < 4; ++g)
          acc[g] = __builtin_amdgcn_mfma_f32_16x16x32_bf16(uu.s8, bfh[(uh ^ 1) * 4 + kp][g], acc[g], 0, 0, 0);
      }
    }

    // gates + state
    float hv4[4];
    unsigned short hb4[4];
#pragma unroll
    for (int r = 0; r < 4; ++r) {
      float ig = sigx(acc[0][r]), fg = sigx(acc[1][r]);
      float gg = tanhx(acc[2][r]), og = sigx(acc[3][r]);
      float cv = fg * c_st[r] + ig * gg;
      c_st[r] = cv;
      hv4[r] = og * tanhx(cv);
      hb4[r] = f2b(hv4[r]);
    }

    // outputs (off critical path; issued before tagged stores so the next
    // poll's vmcnt drain mostly sees them already retired)
#pragma unroll
    for (int r = 0; r < 4; ++r) {
      const int m = mh * 16 + quad * 4 + r;
      if constexpr (!LAYER1)
        h0out[((size_t)m * Tn + t) * 512 + scan * Hn + U] = hb4[r];
      else
        dout[((size_t)m * Tn + t) * 512 + scan * Hn + U] = hv4[r];
    }

    // tagged partner stores (fire-and-forget)
    {
      unsigned long long* dst = mybox + (s & 1) * 1024;
#pragma unroll
      for (int r = 0; r < 4; ++r) {
        unsigned pk = ((unsigned)__shfl_xor((int)hb4[r], 1)) & 0xffffu;
        if (!(lane & 1)) {
          unsigned pair = (unsigned)hb4[r] | (pk << 16);
          unsigned long long v = (((unsigned long long)(unsigned)(s + 1)) << 32) | pair;
          __hip_atomic_store(dst + (quad * 4 + r) * 64 + w * 8 + (l15 >> 1), v,
                             __ATOMIC_RELAXED, __HIP_MEMORY_SCOPE_AGENT);
        }
      }
    }

    // own-half h into LDS (fragment-shuffled layout), parity s&1
    {
      const int blk = ((Ul >> 5) * 4 + ((Ul >> 3) & 3)) * 16;
#pragma unroll
      for (int r = 0; r < 4; ++r)
        ldsb[(s & 1) * 2048 + (blk + quad * 4 + r) * 8 + (Ul & 7)] = hb4[r];
    }

    // LDS-only barrier: wait ds ops, NOT vmem (keeps stores/loads in flight)
    asm volatile("s_waitcnt lgkmcnt(0)\n\ts_barrier" ::: "memory");
  }
}

extern "C" void kernel_launch(void* const* d_in, const int* in_sizes, int n_in,
                              void* d_out, int out_size, void* d_ws, size_t ws_size,
                              hipStream_t stream) {
  (void)in_sizes; (void)n_in; (void)out_size; (void)ws_size;
  const float* x      = (const float*)d_in[0];
  const float* Wih_f0 = (const float*)d_in[1];
  const float* Whh_f0 = (const float*)d_in[2];
  const float* b_f0   = (const float*)d_in[3];
  const float* Wih_r0 = (const float*)d_in[4];
  const float* Whh_r0 = (const float*)d_in[5];
  const float* b_r0   = (const float*)d_in[6];
  const float* Wih_f1 = (const float*)d_in[7];
  const float* Whh_f1 = (const float*)d_in[8];
  const float* b_f1   = (const float*)d_in[9];
  const float* Wih_r1 = (const float*)d_in[10];
  const float* Whh_r1 = (const float*)d_in[11];
  const float* b_r1   = (const float*)d_in[12];

  char* ws = (char*)d_ws;
  unsigned short* xgbuf = (unsigned short*)ws;                 // 268,435,456 B
  size_t off = (size_t)2 * Tn * Bn * 1024 * sizeof(unsigned short);
  unsigned short* h0out = (unsigned short*)(ws + off);         // 67,108,864 B
  off += (size_t)Bn * Tn * 512 * sizeof(unsigned short);
  unsigned long long* boxA = (unsigned long long*)(ws + off); off += 8 * 2048 * 8;
  unsigned long long* boxB = (unsigned long long*)(ws + off); off += 8 * 2048 * 8;

  // zero both outboxes (tags 1..2048 must not alias stale/poison data)
  hipMemsetAsync(boxA, 0, 2 * 8 * 2048 * 8, stream);

  dim3 blk(256);
  // layer 0
  xg_gemm<256, true><<<dim3(4096), blk, 0, stream>>>(
      (const void*)x, Wih_f0, b_f0, Wih_r0, b_r0, xgbuf);
  lstm_scan<false><<<dim3(8), dim3(512), 0, stream>>>(
      xgbuf, Whh_f0, Whh_r0, boxA, h0out, (float*)nullptr);
  // layer 1
  xg_gemm<512, false><<<dim3(4096), blk, 0, stream>>>(
      (const void*)h0out, Wih_f1, b_f1, Wih_r1, b_r1, xgbuf);
  lstm_scan<true><<<dim3(8), dim3(512), 0, stream>>>(
      xgbuf, Whh_f1, Whh_r1, boxB, (unsigned short*)nullptr, (float*)d_out);
}